// Round 8
// baseline (277.278 us; speedup 1.0000x reference)
//
#include <hip/hip_runtime.h>
#include <stdint.h>

#define B_ 8
#define N_ 4096
#define C_ 128
#define OSEM 13
#define OINS 5
#define KNN 30
#define NSC 32   // f32-screened candidates, rescored in f64
#define ROWS 4   // rows per wave in k_knn_out

typedef unsigned short u16;
typedef unsigned int u32;
typedef unsigned long long u64;

__device__ __forceinline__ float bf2f(u16 v) {
  u32 u = ((u32)v) << 16;
  return __uint_as_float(u);
}
__device__ __forceinline__ u16 f2bf(float f) {
  u32 u = __float_as_uint(f);
  u32 r = (u + 0x7FFFu + ((u >> 16) & 1u)) >> 16;  // RNE
  return (u16)r;
}
__device__ __forceinline__ u32 monof(float d) {
  u32 u = __float_as_uint(d);
  return (u & 0x80000000u) ? ~u : (u | 0x80000000u);
}
__device__ __forceinline__ float unmonof(u32 p) {
  u32 u = (p & 0x80000000u) ? (p & 0x7FFFFFFFu) : ~p;
  return __uint_as_float(u);
}
__device__ __forceinline__ u64 monod(double d) {
  u64 u = (u64)__double_as_longlong(d);
  return (u & 0x8000000000000000ull) ? ~u : (u | 0x8000000000000000ull);
}
__device__ __forceinline__ int mbcnt64(u64 m) {
  return __builtin_amdgcn_mbcnt_hi((u32)(m >> 32),
                                   __builtin_amdgcn_mbcnt_lo((u32)m, 0));
}
// force wave-uniform float into SGPR
__device__ __forceinline__ float rflf(float x) {
  return __uint_as_float(
      (u32)__builtin_amdgcn_readfirstlane((int)__float_as_uint(x)));
}

template <int M>
__device__ __forceinline__ float ldv(const void* p, size_t i) {
  if (M == 0) return bf2f(((const u16*)p)[i]);
  return ((const float*)p)[i];
}
template <int M>
__device__ __forceinline__ double ldvd(const void* p, size_t i) {
  return (double)ldv<M>(p, i);
}
template <int M>
__device__ __forceinline__ void stv(void* p, size_t i, float v) {
  if (M == 0) ((u16*)p)[i] = f2bf(v);
  else ((float*)p)[i] = v;
}
template <int M>
__device__ __forceinline__ void ld8(const void* p, size_t i, float* o) {
  if (M == 0) {
    uint4 u = *(const uint4*)((const u16*)p + i);
    o[0] = __uint_as_float(u.x << 16); o[1] = __uint_as_float(u.x & 0xFFFF0000u);
    o[2] = __uint_as_float(u.y << 16); o[3] = __uint_as_float(u.y & 0xFFFF0000u);
    o[4] = __uint_as_float(u.z << 16); o[5] = __uint_as_float(u.z & 0xFFFF0000u);
    o[6] = __uint_as_float(u.w << 16); o[7] = __uint_as_float(u.w & 0xFFFF0000u);
  } else {
    const float4* f = (const float4*)((const float*)p + i);
    float4 a = f[0], b = f[1];
    o[0] = a.x; o[1] = a.y; o[2] = a.z; o[3] = a.w;
    o[4] = b.x; o[5] = b.y; o[6] = b.z; o[7] = b.w;
  }
}

#define PREP_SMEM 53504  // max(xs 20480 + wt 33024, fsh 16384 + fsl 16384)

// ---------------------------------------------------------------------------
// Transpose body: f_sem[b][c][n] -> fT[b][n][c] in NATIVE dtype.
// ---------------------------------------------------------------------------
template <typename T>
__device__ __forceinline__ void transpose_body(const void* src_, void* dst_,
                                               char* tsm, int b, int c0,
                                               int n0) {
  T* t = (T*)tsm;  // [64][65]
  const T* src0 = (const T*)src_;
  T* dst0 = (T*)dst_;
  int tid = threadIdx.x, j = tid & 63, i0 = tid >> 6;
  const T* src = src0 + (size_t)(b * C_ + c0) * N_ + n0;
#pragma unroll
  for (int k = 0; k < 16; ++k) {
    int i = k * 4 + i0;
    t[i * 65 + j] = src[(size_t)i * N_ + j];
  }
  __syncthreads();
  T* dst = dst0 + ((size_t)b * N_ + n0) * C_ + c0;
#pragma unroll
  for (int k = 0; k < 16; ++k) {
    int nl = k * 4 + i0;
    dst[(size_t)nl * C_ + j] = t[j * 65 + nl];
  }
}

// ---------------------------------------------------------------------------
// Fused chain (ALL f64, bit-identical to the verified R5 version):
// adapted = W_adapt@f_sem ; relu affine ; fs = f_ins + h ; e = W_ins@fs ; sq.
// Changes are perf-only: wt padded [32][129] + coalesced W staging (lanes
// read contiguous k); phase-2 fs matrix split into two c-halves (e folds
// c=0..63 then 64..127 -- same ascending order -> identical f64 results).
// LDS: phase1 20480+33024 = 52.3KB; phase2 32KB -> 3 blocks/CU (was 2).
// ---------------------------------------------------------------------------
template <int M>
__device__ void fused_body(const void* fsem, const void* fins, const void* Wad,
                           const void* bad, const void* gad, const void* bead,
                           const void* Wins, const void* bins,
                           float* __restrict__ q32, double* __restrict__ q64,
                           void* oute, char* smem, int b, int n0) {
  double* xs = (double*)smem;            // [32][8 grp][10] f64 (20480B)
  double* wt = (double*)(smem + 20480);  // [32][129] f64 (33024B, padded)
  float* fsh = (float*)smem;             // phase 2: [64][64] hi (16KB)
  float* fsl = (float*)(smem + 16384);   // phase 2: [64][64] lo (16KB)

  int tid = threadIdx.x, tx = tid & 7, ty = tid >> 3;  // tx: n-grp, ty: c-grp

  double acc[4][8];
#pragma unroll
  for (int i = 0; i < 4; ++i)
#pragma unroll
    for (int j = 0; j < 8; ++j) acc[i][j] = 0.0;

  for (int kk = 0; kk < 128; kk += 32) {
    __syncthreads();
    {  // stage x chunk: 32 k-rows x 64 n-cols
      int r = tid >> 3, c8 = tid & 7;
      float v[8];
      ld8<M>(fsem, (size_t)(b * C_ + kk + r) * N_ + n0 + c8 * 8, v);
#pragma unroll
      for (int j = 0; j < 8; ++j) xs[r * 80 + c8 * 10 + j] = (double)v[j];
    }
#pragma unroll
    for (int it = 0; it < 16; ++it) {  // stage W^T chunk, coalesced in k
      int f = it * 256 + tid;
      int k = f & 31, c = f >> 5;
      wt[k * 129 + c] = ldvd<M>(Wad, (size_t)c * C_ + kk + k);
    }
    __syncthreads();
#pragma unroll 2
    for (int k = 0; k < 32; ++k) {
      double xv[8], wv[4];
#pragma unroll
      for (int j = 0; j < 8; ++j) xv[j] = xs[k * 80 + tx * 10 + j];
#pragma unroll
      for (int i = 0; i < 4; ++i) wv[i] = wt[k * 129 + ty * 4 + i];
#pragma unroll
      for (int i = 0; i < 4; ++i)
#pragma unroll
        for (int j = 0; j < 8; ++j) acc[i][j] = fma(wv[i], xv[j], acc[i][j]);
    }
  }

#pragma unroll
  for (int i = 0; i < 4; ++i) {
    int c = ty * 4 + i;
    double ba = ldvd<M>(bad, c), ga = ldvd<M>(gad, c), be = ldvd<M>(bead, c);
    float ff[8];
    ld8<M>(fins, (size_t)(b * C_ + c) * N_ + n0 + tx * 8, ff);
#pragma unroll
    for (int j = 0; j < 8; ++j) {
      double a = acc[i][j] + ba;
      double h = a * ga + be;
      h = h > 0.0 ? h : 0.0;
      acc[i][j] = (double)ff[j] + h;
    }
  }

  // ---- phase 2 in two c-halves (same ascending c fold -> bit-identical) --
  double e[5] = {0.0, 0.0, 0.0, 0.0, 0.0};
#pragma unroll 1
  for (int h = 0; h < 2; ++h) {
    __syncthreads();  // h=0: GEMM LDS reads done; h=1: half-0 e-reads done
    if ((ty >> 4) == h) {
#pragma unroll
      for (int i = 0; i < 4; ++i) {
        int cl = ty * 4 + i - h * 64;
#pragma unroll
        for (int j = 0; j < 8; ++j) {
          double fs = acc[i][j];
          float hi = (float)fs;
          fsh[cl * 64 + tx * 8 + j] = hi;
          fsl[cl * 64 + tx * 8 + j] = (float)(fs - (double)hi);
        }
      }
    }
    __syncthreads();
    if (tid < 64) {
#pragma unroll 4
      for (int cl = 0; cl < 64; ++cl) {
        int c = h * 64 + cl;
        double fs = (double)fsh[cl * 64 + tid] + (double)fsl[cl * 64 + tid];
#pragma unroll
        for (int o = 0; o < 5; ++o)
          e[o] = fma(ldvd<M>(Wins, (size_t)o * C_ + c), fs, e[o]);
      }
    }
  }

  if (tid < 64) {
    int n = n0 + tid;
    double sq = 0.0;
#pragma unroll
    for (int o = 0; o < 5; ++o) {
      e[o] = e[o] + ldvd<M>(bins, o);
      sq = fma(e[o], e[o], sq);
      stv<M>(oute, (size_t)(b * OINS + o) * N_ + n, (float)e[o]);
    }
    size_t row = (size_t)b * N_ + n;
    float* qp = q32 + row * 8;
    qp[0] = (float)e[0]; qp[1] = (float)e[1]; qp[2] = (float)e[2];
    qp[3] = (float)e[3]; qp[4] = (float)e[4]; qp[5] = (float)sq;
    qp[6] = 0.f; qp[7] = 0.f;
    double* qd = q64 + row * 8;
    qd[0] = e[0]; qd[1] = e[1]; qd[2] = e[2]; qd[3] = e[3]; qd[4] = e[4];
    qd[5] = sq; qd[6] = 0.0; qd[7] = 0.0;
  }
}

// ---------------------------------------------------------------------------
// Merged prep kernel: XCD-pinned (bx&7 == batch), 1:2 GEMM/transpose
// interleave within each XCD so compute-bound GEMM and memory-bound
// transpose overlap on each CU. 1536 blocks, 52.3KB LDS -> 3 blocks/CU.
// Block 0 publishes the dtype flag for k_knn_out.
// ---------------------------------------------------------------------------
__global__ __launch_bounds__(256) void k_prep(
    const void* fsem, const void* fins, const void* Wad, const void* bad,
    const void* gad, const void* bead, const void* Wins, const void* bins,
    float* q32, double* q64, void* oute_bf, void* oute_f, void* fT,
    int useFT0, int useFT1, u32* flag) {
  __shared__ __align__(16) char smem[PREP_SMEM];
  __shared__ int sred[4];

  int tid = threadIdx.x;
  // ---- self-sniff: 256 threads x 4 even-u16 samples (bf16 ~1014, f32 ~256)
  int csn = 0;
  {
    const u16* p = (const u16*)fsem;
#pragma unroll
    for (int i = 0; i < 4; ++i) {
      u16 v = p[2 * (tid * 4 + i)];
      u32 e = (v >> 7) & 0xFF;
      csn += (e >= 0x60 && e <= 0x9F) ? 1 : 0;
    }
#pragma unroll
    for (int s = 1; s < 64; s <<= 1) csn += __shfl_xor(csn, s, 64);
    if ((tid & 63) == 0) sred[tid >> 6] = csn;
  }
  __syncthreads();
  u32 fl = ((sred[0] + sred[1] + sred[2] + sred[3]) >= 614) ? 0u : 1u;

  int bx = blockIdx.x;
  if (bx == 0 && tid == 0) flag[0] = fl;

  int x = bx & 7;        // XCD == batch
  int local = bx >> 3;   // 0..191 within XCD
  int q3 = local / 3, r3 = local - q3 * 3;
  if (r3 == 0) {
    // GEMM tile q3 of batch x: n0 = q3*64
    if (fl == 0)
      fused_body<0>(fsem, fins, Wad, bad, gad, bead, Wins, bins, q32, q64,
                    oute_bf, smem, x, q3 * 64);
    else
      fused_body<1>(fsem, fins, Wad, bad, gad, bead, Wins, bins, q32, q64,
                    oute_f, smem, x, q3 * 64);
  } else {
    // transpose tile tloc of batch x: tloc in [0,128)
    int tloc = q3 * 2 + (r3 - 1);
    int n0 = (tloc & 63) * 64, c0 = (tloc >> 6) * 64;
    if (fl == 0) {
      if (!useFT0) return;
      transpose_body<u16>(fsem, fT, smem, x, c0, n0);
    } else {
      if (!useFT1) return;
      transpose_body<float>(fsem, fT, smem, x, c0, n0);
    }
  }
}

// ---------------------------------------------------------------------------
// Packed gather pass: one lane covers 4 channels of one row (rows split by
// lane>>5 at caller). 8B/16B loads -> half the load instrs vs u32 path.
// ---------------------------------------------------------------------------
template <int M>
__device__ __forceinline__ void gather_pass(int b, const u32* __restrict__ fp,
                                            const void* fT, int c0,
                                            float* mx) {
#pragma unroll 3
  for (int k = 0; k < KNN; ++k) {
    int id = (int)fp[k];
    if (M == 0) {
      uint2 v = *(const uint2*)((const u16*)fT + (size_t)(b * N_ + id) * C_ + c0);
      mx[0] = fmaxf(mx[0], __uint_as_float(v.x << 16));
      mx[1] = fmaxf(mx[1], __uint_as_float(v.x & 0xFFFF0000u));
      mx[2] = fmaxf(mx[2], __uint_as_float(v.y << 16));
      mx[3] = fmaxf(mx[3], __uint_as_float(v.y & 0xFFFF0000u));
    } else {
      float4 v = *(const float4*)((const float*)fT + (size_t)(b * N_ + id) * C_ + c0);
      mx[0] = fmaxf(mx[0], v.x);
      mx[1] = fmaxf(mx[1], v.y);
      mx[2] = fmaxf(mx[2], v.z);
      mx[3] = fmaxf(mx[3], v.w);
    }
  }
}

// ---------------------------------------------------------------------------
// Legacy per-row gather/max + projection (used only for the !useFT fallback).
// ---------------------------------------------------------------------------
template <int M>
__device__ __forceinline__ void gather_proj(int b, int n, const u32* fin,
                                            const void* fsem,
                                            const float* wsm,
                                            const float* bsm, float* fls,
                                            void* outv, int lane) {
  float mx0 = -__builtin_inff(), mx1 = -__builtin_inff();
  int c0 = lane * 2;
  size_t base = ((size_t)b * C_ + c0) * N_;
#pragma unroll 2
  for (int k = 0; k < KNN; ++k) {
    int id = (int)fin[k];
    mx0 = fmaxf(mx0, ldv<M>(fsem, base + id));
    mx1 = fmaxf(mx1, ldv<M>(fsem, base + N_ + id));
  }
  int g0 = c0 >> 5, cc0 = c0 & 31;
  fls[g0 * 33 + cc0] = mx0;
  fls[g0 * 33 + cc0 + 1] = mx1;
  if (lane < 52) {
    int o = lane >> 2, g = lane & 3;
    const float* wr = &wsm[(o * 4 + g) * 33];
    const float* fr = &fls[g * 33];
    float s = 0.f;
#pragma unroll
    for (int c = 0; c < 32; ++c) s = fmaf(wr[c], fr[c], s);
    s += __shfl_xor(s, 1, 64);
    s += __shfl_xor(s, 2, 64);
    if (g == 0) stv<M>(outv, ((size_t)b * OSEM + o) * N_ + n, s + bsm[o]);
  }
}

// ---------------------------------------------------------------------------
// Fused KNN screen + finalize -- TWO-PHASE scan, linear pointer-marched
// addressing, XCD-aware block swizzle (unchanged from R7, verified 146us).
// ---------------------------------------------------------------------------
__global__ __launch_bounds__(256) void k_knn_out(
    const u32* flag, const float* __restrict__ q32,
    const double* __restrict__ q64, const void* fsem, const void* fT,
    int useFT0, int useFT1, const void* Wsem, const void* bsem, void* outv) {
  __shared__ u64 bufs[4][ROWS][128];  // 16KB; overlaid after finalize
  __shared__ u32 idq[4][NSC];
  __shared__ u32 fin[4][ROWS][32];
  __shared__ float bsm[16];

  int tid = threadIdx.x, wid = tid >> 6, lane = tid & 63;
  u32 fl = *flag;
  int useFT = fl == 0 ? useFT0 : useFT1;

  // XCD swizzle: 2048 blocks, 8 XCDs; bid&7 -> XCD (round-robin dispatch),
  // swz groups 256 consecutive logical blocks (one batch) per XCD.
  int bid = blockIdx.x;
  int swz = ((bid & 7) << 8) | (bid >> 3);
  int gw = swz * 4 + wid;         // 0..8191
  int b = gw >> 10;               // 1024 waves per batch (b == bid&7)
  int r0 = (gw & 1023) * ROWS;
  const float* qb = q32 + (((size_t)b) << 12) * 8;
  u64(*buf)[128] = bufs[wid];

#pragma unroll
  for (int i = 0; i < 2 * ROWS; ++i) bufs[wid][0][i * 64 + lane] = ~0ull;

  float er2[ROWS][5], t[ROWS];
  int cnt[ROWS];
#pragma unroll
  for (int r = 0; r < ROWS; ++r) {
    const float* qr = qb + (size_t)(r0 + r) * 8;
    er2[r][0] = -2.f * qr[0]; er2[r][1] = -2.f * qr[1];
    er2[r][2] = -2.f * qr[2]; er2[r][3] = -2.f * qr[3];
    er2[r][4] = -2.f * qr[4];
    cnt[r] = 0;
  }

  // Inlined rank-count compress. Requires >= 65 real keys in the buffer
  // (guaranteed: only invoked when cnt + newhits > 128 with cnt > 64).
  auto rank_compress = [&](u64* bufr) -> float {
    u64 k0 = bufr[lane], k1 = bufr[lane + 64];
    int f0 = 0, f1 = 0;
#pragma unroll 4
    for (int j = 0; j < 64; ++j) {  // uniform addr -> LDS broadcast b128
      ulonglong2 kk = *(const ulonglong2*)&bufr[2 * j];
      f0 += (kk.x < k0) ? 1 : 0;
      f0 += (kk.y < k0) ? 1 : 0;
      f1 += (kk.x < k1) ? 1 : 0;
      f1 += (kk.y < k1) ? 1 : 0;
    }
    // broadcast exact 32nd-smallest distance (rank 31; exactly one lane-slot)
    bool h31 = (f0 == 31) || (f1 == 31);
    u64 who = __ballot(h31);
    u32 pk = (f0 == 31) ? (u32)(k0 >> 32) : (u32)(k1 >> 32);
    int src = (int)(__ffsll((long long)who) - 1);
    pk = (u32)__shfl((int)pk, src, 64);
    // scatter survivors by rank; pads above
    bufr[64 + lane] = ~0ull;
    if (f0 < 64) bufr[f0] = k0;
    if (f1 < 64) bufr[f1] = k1;
    return unmonof(pk);
  };

#define DIST(dst, X, Y, r)                      \
  {                                             \
    float dd_ = (Y).y;                          \
    dd_ = fmaf(er2[r][0], (X).x, dd_);          \
    dd_ = fmaf(er2[r][1], (X).y, dd_);          \
    dd_ = fmaf(er2[r][2], (X).z, dd_);          \
    dd_ = fmaf(er2[r][3], (X).w, dd_);          \
    dd_ = fmaf(er2[r][4], (Y).x, dd_);          \
    (dst) = dd_;                                \
  }

  // ---- phase 1: pure streaming min-scan, 4 pairs (256 cands) per iter ----
  float minv[ROWS];
#pragma unroll
  for (int r = 0; r < ROWS; ++r) minv[r] = __builtin_inff();
  {
    const float* g = qb + lane * 8;
#pragma unroll 1
    for (int it = 0; it < 16; ++it) {
      float4 Aa = *(const float4*)(g);        float2 Ba = *(const float2*)(g + 4);
      float4 Ab = *(const float4*)(g + 512);  float2 Bb = *(const float2*)(g + 516);
      float4 Ac = *(const float4*)(g + 1024); float2 Bc = *(const float2*)(g + 1028);
      float4 Ad = *(const float4*)(g + 1536); float2 Bd = *(const float2*)(g + 1540);
      g += 2048;
#pragma unroll
      for (int r = 0; r < ROWS; ++r) {
        float da, db, dc, dd;
        DIST(da, Aa, Ba, r);
        DIST(db, Ab, Bb, r);
        DIST(dc, Ac, Bc, r);
        DIST(dd, Ad, Bd, r);
        minv[r] = fminf(minv[r], fminf(fminf(da, db), fminf(dc, dd)));
      }
    }
  }

  // ---- phase 1.5: t[r] = exact 32nd-smallest lane-min (joint 4-row) ----
  {
    u64 KM[ROWS];
    int fr2[ROWS];
#pragma unroll
    for (int r = 0; r < ROWS; ++r) {
      KM[r] = ((u64)monof(minv[r]) << 6) | (u32)lane;  // distinct keys
      buf[r][lane] = KM[r];
      fr2[r] = 0;
    }
#pragma unroll 2
    for (int j = 0; j < 32; ++j) {  // uniform addr -> LDS broadcast b128
#pragma unroll
      for (int r = 0; r < ROWS; ++r) {
        ulonglong2 kk = *(const ulonglong2*)&buf[r][2 * j];
        fr2[r] += (kk.x < KM[r]) ? 1 : 0;
        fr2[r] += (kk.y < KM[r]) ? 1 : 0;
      }
    }
#pragma unroll
    for (int r = 0; r < ROWS; ++r) {
      bool h = (fr2[r] == 31);
      u64 who = __ballot(h);
      int src = (int)(__ffsll((long long)who) - 1);
      u32 pk = (u32)(KM[r] >> 6);
      pk = (u32)__shfl((int)pk, src, 64);
      t[r] = rflf(unmonof(pk));
      buf[r][lane] = ~0ull;  // restore pads for phase 2 (slots 64..127 clean)
    }
  }

  // ---- phase 2: gated collect with tight threshold, linear 2-wide ----
  {
    const float* g = qb + lane * 8;
    int mbase = 0;
#pragma unroll 1
    for (int it = 0; it < 32; ++it) {
      float4 A0 = *(const float4*)(g);       float2 B0 = *(const float2*)(g + 4);
      float4 A1 = *(const float4*)(g + 512); float2 B1 = *(const float2*)(g + 516);
      g += 1024;
      float d0[ROWS], d1[ROWS];
      u64 h0[ROWS], h1[ROWS];
#pragma unroll
      for (int r = 0; r < ROWS; ++r) {
        DIST(d0[r], A0, B0, r);
        DIST(d1[r], A1, B1, r);
        h0[r] = __ballot(d0[r] <= t[r]);
        h1[r] = __ballot(d1[r] <= t[r]);
      }
#pragma unroll
      for (int r = 0; r < ROWS; ++r) {
        u64 a = h0[r], c = h1[r];
        int m0 = mbase + lane, m1 = mbase + 64 + lane;
        if (a | c) {
          int ha = __popcll(a), hc = __popcll(c);
          if (cnt[r] + ha + hc <= 128) {
            int oa = mbcnt64(a), oc = ha + mbcnt64(c);
            if (d0[r] <= t[r])
              buf[r][cnt[r] + oa] = ((u64)monof(d0[r]) << 32) | (u32)m0;
            if (d1[r] <= t[r])
              buf[r][cnt[r] + oc] = ((u64)monof(d1[r]) << 32) | (u32)m1;
            cnt[r] += ha + hc;
          } else {
            // overflow (rare): compress to 64 (exact-32 threshold), then
            // sequential sub-group appends (each <= 64 hits -> cnt <= 128).
            if (cnt[r] + ha > 128) {
              t[r] = rflf(rank_compress(&buf[r][0]));
              cnt[r] = 64;
              a = __ballot(d0[r] <= t[r]);
              ha = __popcll(a);
            }
            if (ha) {
              int oa = mbcnt64(a);
              if (d0[r] <= t[r])
                buf[r][cnt[r] + oa] = ((u64)monof(d0[r]) << 32) | (u32)m0;
              cnt[r] += ha;
            }
            u64 c2 = __ballot(d1[r] <= t[r]);
            int hc2 = __popcll(c2);
            if (cnt[r] + hc2 > 128) {
              t[r] = rflf(rank_compress(&buf[r][0]));
              cnt[r] = 64;
              c2 = __ballot(d1[r] <= t[r]);
              hc2 = __popcll(c2);
            }
            if (hc2) {
              int oc = mbcnt64(c2);
              if (d1[r] <= t[r])
                buf[r][cnt[r] + oc] = ((u64)monof(d1[r]) << 32) | (u32)m1;
              cnt[r] += hc2;
            }
          }
        }
      }
      mbase += 128;
    }
  }
#undef DIST

  // ---- finalize: JOINT 4-row rank-count -> per-row f64 rescore/rank-30 ----
  // cnt[r] >= 32 guaranteed (>= 32 candidates have d <= t by construction).
  // Slots >= cnt[r] hold ~0ull pads; real keys are distinct. Rank-count over
  // distinct u64 keys reproduces exactly the f32-top-32 per row.
  const double* qdb = q64 + (((size_t)b) << 12) * 8;
  {
    u64 K0[ROWS], K1[ROWS];
    int f0[ROWS], f1[ROWS];
    int cmax = 0;
#pragma unroll
    for (int r = 0; r < ROWS; ++r) {
      K0[r] = buf[r][lane];
      K1[r] = buf[r][lane + 64];
      f0[r] = 0; f1[r] = 0;
      cmax = cnt[r] > cmax ? cnt[r] : cmax;
    }
    int JJ = (cmax + 1) >> 1;
#pragma unroll 2
    for (int j = 0; j < JJ; ++j) {  // uniform addr -> LDS broadcast b128
#pragma unroll
      for (int r = 0; r < ROWS; ++r) {
        ulonglong2 kk = *(const ulonglong2*)&buf[r][2 * j];
        f0[r] += (kk.x < K0[r]) ? 1 : 0;
        f0[r] += (kk.y < K0[r]) ? 1 : 0;
        f1[r] += (kk.x < K1[r]) ? 1 : 0;
        f1[r] += (kk.y < K1[r]) ? 1 : 0;
      }
    }
#pragma unroll 1
    for (int r = 0; r < ROWS; ++r) {
      if (f0[r] < NSC) idq[wid][f0[r]] = (u32)K0[r] & (N_ - 1);
      if (f1[r] < NSC) idq[wid][f1[r]] = (u32)K1[r] & (N_ - 1);

      const double* qdr = qdb + (size_t)(r0 + r) * 8;
      double D0 = qdr[0], D1 = qdr[1], D2 = qdr[2], D3 = qdr[3], D4 = qdr[4],
             DS = qdr[5];
      u64 key = ~0ull;
      u32 myid = 0;
      if (lane < NSC) {
        myid = idq[wid][lane];
        const double* qm = qdb + (size_t)myid * 8;
        double dot = D0 * qm[0];
        dot = fma(D1, qm[1], dot);
        dot = fma(D2, qm[2], dot);
        dot = fma(D3, qm[3], dot);
        dot = fma(D4, qm[4], dot);
        double dd = (DS - 2.0 * dot) + qm[5];
        key = (monod(dd) & ~0xFFFull) | myid;
      }
      buf[r][lane] = key;  // lanes >= NSC park ~0ull in dead slots 32..63
      int rank = 0;
#pragma unroll
      for (int j = 0; j < NSC / 2; ++j) {
        ulonglong2 kk = *(const ulonglong2*)&buf[r][2 * j];
        rank += (kk.x < key) ? 1 : 0;
        rank += (kk.y < key) ? 1 : 0;
      }
      if (lane < NSC && rank < KNN) fin[wid][r][rank] = myid;
    }
  }

  // ---- overlay: stage wsm/bsm into the now-dead bufs region ----
  __syncthreads();
  float* wsm = (float*)&bufs[0][0][0];          // 13*4*33 = 1716 floats
  float* flsb = (float*)&bufs[0][0][0] + 1728;  // 16 rows x 136 = 2176 floats
  for (int i = tid; i < 13 * 128; i += 256) {
    int o = i >> 7, cc = i & 127;
    wsm[(o * 4 + (cc >> 5)) * 33 + (cc & 31)] =
        (fl == 0) ? ldv<0>(Wsem, i) : ldv<1>(Wsem, i);
  }
  if (tid < OSEM) bsm[tid] = (fl == 0) ? ldv<0>(bsem, tid) : ldv<1>(bsem, tid);
  __syncthreads();

  if (useFT) {
    // ---- packed gather: 2 rows per pass (lane>>5 selects row) ----
    int h = lane >> 5, l5 = lane & 31, c0 = l5 * 4;
#pragma unroll 1
    for (int pass = 0; pass < 2; ++pass) {
      int r = pass * 2 + h;
      float mx[4] = {-__builtin_inff(), -__builtin_inff(), -__builtin_inff(),
                     -__builtin_inff()};
      if (fl == 0)
        gather_pass<0>(b, &fin[wid][r][0], fT, c0, mx);
      else
        gather_pass<1>(b, &fin[wid][r][0], fT, c0, mx);
      float* fr = flsb + (wid * ROWS + r) * 136 + (c0 >> 5) * 33 + (c0 & 31);
      fr[0] = mx[0]; fr[1] = mx[1]; fr[2] = mx[2]; fr[3] = mx[3];
    }
    // ---- joint 4-row projection ----
    if (lane < 52) {
      int o = lane >> 2, g = lane & 3;
      const float* wr = &wsm[(o * 4 + g) * 33];
      const float* p0 = flsb + (wid * ROWS + 0) * 136 + g * 33;
      const float* p1 = flsb + (wid * ROWS + 1) * 136 + g * 33;
      const float* p2 = flsb + (wid * ROWS + 2) * 136 + g * 33;
      const float* p3 = flsb + (wid * ROWS + 3) * 136 + g * 33;
      float s0 = 0.f, s1 = 0.f, s2 = 0.f, s3 = 0.f;
#pragma unroll
      for (int c = 0; c < 32; ++c) {
        float w = wr[c];
        s0 = fmaf(w, p0[c], s0);
        s1 = fmaf(w, p1[c], s1);
        s2 = fmaf(w, p2[c], s2);
        s3 = fmaf(w, p3[c], s3);
      }
      s0 += __shfl_xor(s0, 1, 64); s0 += __shfl_xor(s0, 2, 64);
      s1 += __shfl_xor(s1, 1, 64); s1 += __shfl_xor(s1, 2, 64);
      s2 += __shfl_xor(s2, 1, 64); s2 += __shfl_xor(s2, 2, 64);
      s3 += __shfl_xor(s3, 1, 64); s3 += __shfl_xor(s3, 2, 64);
      if (g == 0) {
        size_t ob = (size_t)b * OSEM + o;
        if (fl == 0) {
          stv<0>(outv, ob * N_ + r0 + 0, s0 + bsm[o]);
          stv<0>(outv, ob * N_ + r0 + 1, s1 + bsm[o]);
          stv<0>(outv, ob * N_ + r0 + 2, s2 + bsm[o]);
          stv<0>(outv, ob * N_ + r0 + 3, s3 + bsm[o]);
        } else {
          stv<1>(outv, ob * N_ + r0 + 0, s0 + bsm[o]);
          stv<1>(outv, ob * N_ + r0 + 1, s1 + bsm[o]);
          stv<1>(outv, ob * N_ + r0 + 2, s2 + bsm[o]);
          stv<1>(outv, ob * N_ + r0 + 3, s3 + bsm[o]);
        }
      }
    }
  } else {
    // ---- fallback: legacy per-row gather from fsem layout ----
    float* fls = flsb + (wid * ROWS) * 136;
#pragma unroll 1
    for (int r = 0; r < ROWS; ++r) {
      if (fl == 0)
        gather_proj<0>(b, r0 + r, &fin[wid][r][0], fsem, wsm, bsm, fls, outv,
                       lane);
      else
        gather_proj<1>(b, r0 + r, &fin[wid][r][0], fsem, wsm, bsm, fls, outv,
                       lane);
    }
  }
}

// ---------------------------------------------------------------------------
extern "C" void kernel_launch(void* const* d_in, const int* in_sizes, int n_in,
                              void* d_out, int out_size, void* d_ws,
                              size_t ws_size, hipStream_t stream) {
  (void)in_sizes; (void)n_in; (void)out_size;
  const void* fsem = d_in[0];
  const void* fins = d_in[1];
  const void* Wad = d_in[2];
  const void* bad = d_in[3];
  const void* gad = d_in[4];
  const void* bead = d_in[5];
  const void* Wins = d_in[6];
  const void* bins = d_in[7];
  const void* Wsem = d_in[8];
  const void* bsem = d_in[9];

  char* ws = (char*)d_ws;
  u32* flag = (u32*)ws;                     // @0
  float* q32 = (float*)(ws + (1 << 20));    // @1MB, 1MB
  double* q64 = (double*)(ws + (2 << 20));  // @2MB, 2MB
  void* fT = (void*)(ws + (4 << 20));       // @4MB: bf16 8MB / f32 16MB
  int useFT0 = (ws_size >= (size_t)(13 << 20)) ? 1 : 0;
  int useFT1 = (ws_size >= (size_t)(21 << 20)) ? 1 : 0;

  void* oute_bf = (void*)((u16*)d_out + (size_t)B_ * OSEM * N_);
  void* oute_f32 = (void*)((float*)d_out + (size_t)B_ * OSEM * N_);

  k_prep<<<dim3(1536), 256, 0, stream>>>(fsem, fins, Wad, bad, gad, bead,
                                         Wins, bins, q32, q64, oute_bf,
                                         oute_f32, fT, useFT0, useFT1, flag);
  k_knn_out<<<dim3(2048), 256, 0, stream>>>(flag, q32, q64, fsem, fT, useFT0,
                                            useFT1, Wsem, bsem, d_out);
}

// Round 9
// 252.577 us; speedup vs baseline: 1.0978x; 1.0978x over previous
//
#include <hip/hip_runtime.h>
#include <stdint.h>

#define B_ 8
#define N_ 4096
#define C_ 128
#define OSEM 13
#define OINS 5
#define KNN 30
#define NSC 32   // f32-screened candidates, rescored in f64
#define ROWS 4   // rows per wave in k_knn_out

typedef unsigned short u16;
typedef unsigned int u32;
typedef unsigned long long u64;

__device__ __forceinline__ float bf2f(u16 v) {
  u32 u = ((u32)v) << 16;
  return __uint_as_float(u);
}
__device__ __forceinline__ u16 f2bf(float f) {
  u32 u = __float_as_uint(f);
  u32 r = (u + 0x7FFFu + ((u >> 16) & 1u)) >> 16;  // RNE
  return (u16)r;
}
__device__ __forceinline__ u32 monof(float d) {
  u32 u = __float_as_uint(d);
  return (u & 0x80000000u) ? ~u : (u | 0x80000000u);
}
__device__ __forceinline__ float unmonof(u32 p) {
  u32 u = (p & 0x80000000u) ? (p & 0x7FFFFFFFu) : ~p;
  return __uint_as_float(u);
}
__device__ __forceinline__ u64 monod(double d) {
  u64 u = (u64)__double_as_longlong(d);
  return (u & 0x8000000000000000ull) ? ~u : (u | 0x8000000000000000ull);
}
__device__ __forceinline__ int mbcnt64(u64 m) {
  return __builtin_amdgcn_mbcnt_hi((u32)(m >> 32),
                                   __builtin_amdgcn_mbcnt_lo((u32)m, 0));
}
// force wave-uniform float into SGPR
__device__ __forceinline__ float rflf(float x) {
  return __uint_as_float(
      (u32)__builtin_amdgcn_readfirstlane((int)__float_as_uint(x)));
}

template <int M>
__device__ __forceinline__ float ldv(const void* p, size_t i) {
  if (M == 0) return bf2f(((const u16*)p)[i]);
  return ((const float*)p)[i];
}
template <int M>
__device__ __forceinline__ double ldvd(const void* p, size_t i) {
  return (double)ldv<M>(p, i);
}
template <int M>
__device__ __forceinline__ void stv(void* p, size_t i, float v) {
  if (M == 0) ((u16*)p)[i] = f2bf(v);
  else ((float*)p)[i] = v;
}
template <int M>
__device__ __forceinline__ void ld8(const void* p, size_t i, float* o) {
  if (M == 0) {
    uint4 u = *(const uint4*)((const u16*)p + i);
    o[0] = __uint_as_float(u.x << 16); o[1] = __uint_as_float(u.x & 0xFFFF0000u);
    o[2] = __uint_as_float(u.y << 16); o[3] = __uint_as_float(u.y & 0xFFFF0000u);
    o[4] = __uint_as_float(u.z << 16); o[5] = __uint_as_float(u.z & 0xFFFF0000u);
    o[6] = __uint_as_float(u.w << 16); o[7] = __uint_as_float(u.w & 0xFFFF0000u);
  } else {
    const float4* f = (const float4*)((const float*)p + i);
    float4 a = f[0], b = f[1];
    o[0] = a.x; o[1] = a.y; o[2] = a.z; o[3] = a.w;
    o[4] = b.x; o[5] = b.y; o[6] = b.z; o[7] = b.w;
  }
}

// self-sniff helper: 256 threads x 4 even-u16 samples (bf16 ~1014, f32 ~256)
__device__ __forceinline__ u32 sniff_dtype(const void* fsem, int* sred) {
  int tid = threadIdx.x;
  int csn = 0;
  const u16* p = (const u16*)fsem;
#pragma unroll
  for (int i = 0; i < 4; ++i) {
    u16 v = p[2 * (tid * 4 + i)];
    u32 e = (v >> 7) & 0xFF;
    csn += (e >= 0x60 && e <= 0x9F) ? 1 : 0;
  }
#pragma unroll
  for (int s = 1; s < 64; s <<= 1) csn += __shfl_xor(csn, s, 64);
  if ((tid & 63) == 0) sred[tid >> 6] = csn;
  __syncthreads();
  return ((sred[0] + sred[1] + sred[2] + sred[3]) >= 614) ? 0u : 1u;
}

// ---------------------------------------------------------------------------
// Transpose: f_sem[b][c][n] -> fT[b][n][c] in NATIVE dtype. Own kernel so
// its small LDS (16.6KB) gets high occupancy (R4-verified faster than the
// merged 64KB-union form).
// ---------------------------------------------------------------------------
template <typename T>
__device__ __forceinline__ void transpose_body(const void* src_, void* dst_,
                                               char* tsm, int b, int c0,
                                               int n0) {
  T* t = (T*)tsm;  // [64][65]
  const T* src0 = (const T*)src_;
  T* dst0 = (T*)dst_;
  int tid = threadIdx.x, j = tid & 63, i0 = tid >> 6;
  const T* src = src0 + (size_t)(b * C_ + c0) * N_ + n0;
#pragma unroll
  for (int k = 0; k < 16; ++k) {
    int i = k * 4 + i0;
    t[i * 65 + j] = src[(size_t)i * N_ + j];
  }
  __syncthreads();
  T* dst = dst0 + ((size_t)b * N_ + n0) * C_ + c0;
#pragma unroll
  for (int k = 0; k < 16; ++k) {
    int nl = k * 4 + i0;
    dst[(size_t)nl * C_ + j] = t[j * 65 + nl];
  }
}

__global__ __launch_bounds__(256) void k_transpose(const void* fsem, void* fT,
                                                   int useFT0, int useFT1) {
  __shared__ __align__(16) char tsm[64 * 65 * 4];
  __shared__ int sred[4];
  u32 fl = sniff_dtype(fsem, sred);
  int idx = blockIdx.x;
  int n0 = (idx & 63) * 64, c0 = ((idx >> 6) & 1) * 64, b = idx >> 7;
  if (fl == 0) {
    if (!useFT0) return;
    transpose_body<u16>(fsem, fT, tsm, b, c0, n0);
  } else {
    if (!useFT1) return;
    transpose_body<float>(fsem, fT, tsm, b, c0, n0);
  }
}

// ---------------------------------------------------------------------------
// Fused chain (ALL f64, bit-identical to the verified R5 version):
// adapted = W_adapt@f_sem ; relu affine ; fs = f_ins + h ; e = W_ins@fs ; sq.
// Single perf change vs R5: W^T staging is coalesced in k (lanes read
// contiguous 128B runs of Wad) with wt padded to [32][129] f64 (write =
// 2 lanes/bank = free). Same values in same logical slots -> identical f64
// results. LDS union: max(20480+33024, 32768+32768) = 65536.
// ---------------------------------------------------------------------------
template <int M>
__device__ void fused_body(const void* fsem, const void* fins, const void* Wad,
                           const void* bad, const void* gad, const void* bead,
                           const void* Wins, const void* bins,
                           float* __restrict__ q32, double* __restrict__ q64,
                           void* oute, char* smem, int b, int n0) {
  double* xs = (double*)smem;            // [32][8 grp][10] f64 (20480B)
  double* wt = (double*)(smem + 20480);  // [32][129] f64 (33024B, padded)
  float* fsh = (float*)smem;             // phase 2: [128][64] hi (32KB)
  float* fsl = (float*)(smem + 32768);   // phase 2: [128][64] lo (32KB)

  int tid = threadIdx.x, tx = tid & 7, ty = tid >> 3;  // tx: n-grp, ty: c-grp

  double acc[4][8];
#pragma unroll
  for (int i = 0; i < 4; ++i)
#pragma unroll
    for (int j = 0; j < 8; ++j) acc[i][j] = 0.0;

  for (int kk = 0; kk < 128; kk += 32) {
    __syncthreads();
    {  // stage x chunk: 32 k-rows x 64 n-cols
      int r = tid >> 3, c8 = tid & 7;
      float v[8];
      ld8<M>(fsem, (size_t)(b * C_ + kk + r) * N_ + n0 + c8 * 8, v);
#pragma unroll
      for (int j = 0; j < 8; ++j) xs[r * 80 + c8 * 10 + j] = (double)v[j];
    }
#pragma unroll
    for (int it = 0; it < 16; ++it) {  // stage W^T chunk, coalesced in k
      int f = it * 256 + tid;
      int k = f & 31, c = f >> 5;
      wt[k * 129 + c] = ldvd<M>(Wad, (size_t)c * C_ + kk + k);
    }
    __syncthreads();
#pragma unroll 2
    for (int k = 0; k < 32; ++k) {
      double xv[8], wv[4];
#pragma unroll
      for (int j = 0; j < 8; ++j) xv[j] = xs[k * 80 + tx * 10 + j];
#pragma unroll
      for (int i = 0; i < 4; ++i) wv[i] = wt[k * 129 + ty * 4 + i];
#pragma unroll
      for (int i = 0; i < 4; ++i)
#pragma unroll
        for (int j = 0; j < 8; ++j) acc[i][j] = fma(wv[i], xv[j], acc[i][j]);
    }
  }

#pragma unroll
  for (int i = 0; i < 4; ++i) {
    int c = ty * 4 + i;
    double ba = ldvd<M>(bad, c), ga = ldvd<M>(gad, c), be = ldvd<M>(bead, c);
    float ff[8];
    ld8<M>(fins, (size_t)(b * C_ + c) * N_ + n0 + tx * 8, ff);
#pragma unroll
    for (int j = 0; j < 8; ++j) {
      double a = acc[i][j] + ba;
      double h = a * ga + be;
      h = h > 0.0 ? h : 0.0;
      acc[i][j] = (double)ff[j] + h;
    }
  }
  __syncthreads();  // GEMM LDS reads done; reuse as fsh/fsl

#pragma unroll
  for (int i = 0; i < 4; ++i) {
    int c = ty * 4 + i;
#pragma unroll
    for (int j = 0; j < 8; ++j) {
      double fs = acc[i][j];
      float hi = (float)fs;
      fsh[c * 64 + tx * 8 + j] = hi;
      fsl[c * 64 + tx * 8 + j] = (float)(fs - (double)hi);
    }
  }
  __syncthreads();
  if (tid < 64) {
    int n = n0 + tid;
    double e[5] = {0.0, 0.0, 0.0, 0.0, 0.0};
#pragma unroll 4
    for (int c = 0; c < 128; ++c) {
      double fs = (double)fsh[c * 64 + tid] + (double)fsl[c * 64 + tid];
#pragma unroll
      for (int o = 0; o < 5; ++o)
        e[o] = fma(ldvd<M>(Wins, (size_t)o * C_ + c), fs, e[o]);
    }
    double sq = 0.0;
#pragma unroll
    for (int o = 0; o < 5; ++o) {
      e[o] = e[o] + ldvd<M>(bins, o);
      sq = fma(e[o], e[o], sq);
      stv<M>(oute, (size_t)(b * OINS + o) * N_ + n, (float)e[o]);
    }
    size_t row = (size_t)b * N_ + n;
    float* qp = q32 + row * 8;
    qp[0] = (float)e[0]; qp[1] = (float)e[1]; qp[2] = (float)e[2];
    qp[3] = (float)e[3]; qp[4] = (float)e[4]; qp[5] = (float)sq;
    qp[6] = 0.f; qp[7] = 0.f;
    double* qd = q64 + row * 8;
    qd[0] = e[0]; qd[1] = e[1]; qd[2] = e[2]; qd[3] = e[3]; qd[4] = e[4];
    qd[5] = sq; qd[6] = 0.0; qd[7] = 0.0;
  }
}

__global__ __launch_bounds__(256) void k_fused(
    const void* fsem, const void* fins, const void* Wad, const void* bad,
    const void* gad, const void* bead, const void* Wins, const void* bins,
    float* q32, double* q64, void* oute_bf, void* oute_f, u32* flag) {
  __shared__ __align__(16) char smem[65536];
  __shared__ int sred[4];
  u32 fl = sniff_dtype(fsem, sred);
  int bx = blockIdx.x;
  if (bx == 0 && threadIdx.x == 0) flag[0] = fl;
  int b = bx >> 6, n0 = (bx & 63) * 64;
  if (fl == 0)
    fused_body<0>(fsem, fins, Wad, bad, gad, bead, Wins, bins, q32, q64,
                  oute_bf, smem, b, n0);
  else
    fused_body<1>(fsem, fins, Wad, bad, gad, bead, Wins, bins, q32, q64,
                  oute_f, smem, b, n0);
}

// ---------------------------------------------------------------------------
// Packed gather pass: one lane covers 4 channels of one row (rows split by
// lane>>5 at caller). 8B/16B loads -> half the load instrs vs u32 path.
// ---------------------------------------------------------------------------
template <int M>
__device__ __forceinline__ void gather_pass(int b, const u32* __restrict__ fp,
                                            const void* fT, int c0,
                                            float* mx) {
#pragma unroll 3
  for (int k = 0; k < KNN; ++k) {
    int id = (int)fp[k];
    if (M == 0) {
      uint2 v = *(const uint2*)((const u16*)fT + (size_t)(b * N_ + id) * C_ + c0);
      mx[0] = fmaxf(mx[0], __uint_as_float(v.x << 16));
      mx[1] = fmaxf(mx[1], __uint_as_float(v.x & 0xFFFF0000u));
      mx[2] = fmaxf(mx[2], __uint_as_float(v.y << 16));
      mx[3] = fmaxf(mx[3], __uint_as_float(v.y & 0xFFFF0000u));
    } else {
      float4 v = *(const float4*)((const float*)fT + (size_t)(b * N_ + id) * C_ + c0);
      mx[0] = fmaxf(mx[0], v.x);
      mx[1] = fmaxf(mx[1], v.y);
      mx[2] = fmaxf(mx[2], v.z);
      mx[3] = fmaxf(mx[3], v.w);
    }
  }
}

// ---------------------------------------------------------------------------
// Legacy per-row gather/max + projection (used only for the !useFT fallback).
// ---------------------------------------------------------------------------
template <int M>
__device__ __forceinline__ void gather_proj(int b, int n, const u32* fin,
                                            const void* fsem,
                                            const float* wsm,
                                            const float* bsm, float* fls,
                                            void* outv, int lane) {
  float mx0 = -__builtin_inff(), mx1 = -__builtin_inff();
  int c0 = lane * 2;
  size_t base = ((size_t)b * C_ + c0) * N_;
#pragma unroll 2
  for (int k = 0; k < KNN; ++k) {
    int id = (int)fin[k];
    mx0 = fmaxf(mx0, ldv<M>(fsem, base + id));
    mx1 = fmaxf(mx1, ldv<M>(fsem, base + N_ + id));
  }
  int g0 = c0 >> 5, cc0 = c0 & 31;
  fls[g0 * 33 + cc0] = mx0;
  fls[g0 * 33 + cc0 + 1] = mx1;
  if (lane < 52) {
    int o = lane >> 2, g = lane & 3;
    const float* wr = &wsm[(o * 4 + g) * 33];
    const float* fr = &fls[g * 33];
    float s = 0.f;
#pragma unroll
    for (int c = 0; c < 32; ++c) s = fmaf(wr[c], fr[c], s);
    s += __shfl_xor(s, 1, 64);
    s += __shfl_xor(s, 2, 64);
    if (g == 0) stv<M>(outv, ((size_t)b * OSEM + o) * N_ + n, s + bsm[o]);
  }
}

// ---------------------------------------------------------------------------
// Fused KNN screen + finalize -- TWO-PHASE scan, linear pointer-marched
// addressing, XCD-aware block swizzle (unchanged from R7, verified 146us).
// ---------------------------------------------------------------------------
__global__ __launch_bounds__(256) void k_knn_out(
    const u32* flag, const float* __restrict__ q32,
    const double* __restrict__ q64, const void* fsem, const void* fT,
    int useFT0, int useFT1, const void* Wsem, const void* bsem, void* outv) {
  __shared__ u64 bufs[4][ROWS][128];  // 16KB; overlaid after finalize
  __shared__ u32 idq[4][NSC];
  __shared__ u32 fin[4][ROWS][32];
  __shared__ float bsm[16];

  int tid = threadIdx.x, wid = tid >> 6, lane = tid & 63;
  u32 fl = *flag;
  int useFT = fl == 0 ? useFT0 : useFT1;

  // XCD swizzle: 2048 blocks, 8 XCDs; bid&7 -> XCD (round-robin dispatch),
  // swz groups 256 consecutive logical blocks (one batch) per XCD.
  int bid = blockIdx.x;
  int swz = ((bid & 7) << 8) | (bid >> 3);
  int gw = swz * 4 + wid;         // 0..8191
  int b = gw >> 10;               // 1024 waves per batch (b == bid&7)
  int r0 = (gw & 1023) * ROWS;
  const float* qb = q32 + (((size_t)b) << 12) * 8;
  u64(*buf)[128] = bufs[wid];

#pragma unroll
  for (int i = 0; i < 2 * ROWS; ++i) bufs[wid][0][i * 64 + lane] = ~0ull;

  float er2[ROWS][5], t[ROWS];
  int cnt[ROWS];
#pragma unroll
  for (int r = 0; r < ROWS; ++r) {
    const float* qr = qb + (size_t)(r0 + r) * 8;
    er2[r][0] = -2.f * qr[0]; er2[r][1] = -2.f * qr[1];
    er2[r][2] = -2.f * qr[2]; er2[r][3] = -2.f * qr[3];
    er2[r][4] = -2.f * qr[4];
    cnt[r] = 0;
  }

  // Inlined rank-count compress. Requires >= 65 real keys in the buffer
  // (guaranteed: only invoked when cnt + newhits > 128 with cnt > 64).
  auto rank_compress = [&](u64* bufr) -> float {
    u64 k0 = bufr[lane], k1 = bufr[lane + 64];
    int f0 = 0, f1 = 0;
#pragma unroll 4
    for (int j = 0; j < 64; ++j) {  // uniform addr -> LDS broadcast b128
      ulonglong2 kk = *(const ulonglong2*)&bufr[2 * j];
      f0 += (kk.x < k0) ? 1 : 0;
      f0 += (kk.y < k0) ? 1 : 0;
      f1 += (kk.x < k1) ? 1 : 0;
      f1 += (kk.y < k1) ? 1 : 0;
    }
    // broadcast exact 32nd-smallest distance (rank 31; exactly one lane-slot)
    bool h31 = (f0 == 31) || (f1 == 31);
    u64 who = __ballot(h31);
    u32 pk = (f0 == 31) ? (u32)(k0 >> 32) : (u32)(k1 >> 32);
    int src = (int)(__ffsll((long long)who) - 1);
    pk = (u32)__shfl((int)pk, src, 64);
    // scatter survivors by rank; pads above
    bufr[64 + lane] = ~0ull;
    if (f0 < 64) bufr[f0] = k0;
    if (f1 < 64) bufr[f1] = k1;
    return unmonof(pk);
  };

#define DIST(dst, X, Y, r)                      \
  {                                             \
    float dd_ = (Y).y;                          \
    dd_ = fmaf(er2[r][0], (X).x, dd_);          \
    dd_ = fmaf(er2[r][1], (X).y, dd_);          \
    dd_ = fmaf(er2[r][2], (X).z, dd_);          \
    dd_ = fmaf(er2[r][3], (X).w, dd_);          \
    dd_ = fmaf(er2[r][4], (Y).x, dd_);          \
    (dst) = dd_;                                \
  }

  // ---- phase 1: pure streaming min-scan, 4 pairs (256 cands) per iter ----
  float minv[ROWS];
#pragma unroll
  for (int r = 0; r < ROWS; ++r) minv[r] = __builtin_inff();
  {
    const float* g = qb + lane * 8;
#pragma unroll 1
    for (int it = 0; it < 16; ++it) {
      float4 Aa = *(const float4*)(g);        float2 Ba = *(const float2*)(g + 4);
      float4 Ab = *(const float4*)(g + 512);  float2 Bb = *(const float2*)(g + 516);
      float4 Ac = *(const float4*)(g + 1024); float2 Bc = *(const float2*)(g + 1028);
      float4 Ad = *(const float4*)(g + 1536); float2 Bd = *(const float2*)(g + 1540);
      g += 2048;
#pragma unroll
      for (int r = 0; r < ROWS; ++r) {
        float da, db, dc, dd;
        DIST(da, Aa, Ba, r);
        DIST(db, Ab, Bb, r);
        DIST(dc, Ac, Bc, r);
        DIST(dd, Ad, Bd, r);
        minv[r] = fminf(minv[r], fminf(fminf(da, db), fminf(dc, dd)));
      }
    }
  }

  // ---- phase 1.5: t[r] = exact 32nd-smallest lane-min (joint 4-row) ----
  {
    u64 KM[ROWS];
    int fr2[ROWS];
#pragma unroll
    for (int r = 0; r < ROWS; ++r) {
      KM[r] = ((u64)monof(minv[r]) << 6) | (u32)lane;  // distinct keys
      buf[r][lane] = KM[r];
      fr2[r] = 0;
    }
#pragma unroll 2
    for (int j = 0; j < 32; ++j) {  // uniform addr -> LDS broadcast b128
#pragma unroll
      for (int r = 0; r < ROWS; ++r) {
        ulonglong2 kk = *(const ulonglong2*)&buf[r][2 * j];
        fr2[r] += (kk.x < KM[r]) ? 1 : 0;
        fr2[r] += (kk.y < KM[r]) ? 1 : 0;
      }
    }
#pragma unroll
    for (int r = 0; r < ROWS; ++r) {
      bool h = (fr2[r] == 31);
      u64 who = __ballot(h);
      int src = (int)(__ffsll((long long)who) - 1);
      u32 pk = (u32)(KM[r] >> 6);
      pk = (u32)__shfl((int)pk, src, 64);
      t[r] = rflf(unmonof(pk));
      buf[r][lane] = ~0ull;  // restore pads for phase 2 (slots 64..127 clean)
    }
  }

  // ---- phase 2: gated collect with tight threshold, linear 2-wide ----
  {
    const float* g = qb + lane * 8;
    int mbase = 0;
#pragma unroll 1
    for (int it = 0; it < 32; ++it) {
      float4 A0 = *(const float4*)(g);       float2 B0 = *(const float2*)(g + 4);
      float4 A1 = *(const float4*)(g + 512); float2 B1 = *(const float2*)(g + 516);
      g += 1024;
      float d0[ROWS], d1[ROWS];
      u64 h0[ROWS], h1[ROWS];
#pragma unroll
      for (int r = 0; r < ROWS; ++r) {
        DIST(d0[r], A0, B0, r);
        DIST(d1[r], A1, B1, r);
        h0[r] = __ballot(d0[r] <= t[r]);
        h1[r] = __ballot(d1[r] <= t[r]);
      }
#pragma unroll
      for (int r = 0; r < ROWS; ++r) {
        u64 a = h0[r], c = h1[r];
        int m0 = mbase + lane, m1 = mbase + 64 + lane;
        if (a | c) {
          int ha = __popcll(a), hc = __popcll(c);
          if (cnt[r] + ha + hc <= 128) {
            int oa = mbcnt64(a), oc = ha + mbcnt64(c);
            if (d0[r] <= t[r])
              buf[r][cnt[r] + oa] = ((u64)monof(d0[r]) << 32) | (u32)m0;
            if (d1[r] <= t[r])
              buf[r][cnt[r] + oc] = ((u64)monof(d1[r]) << 32) | (u32)m1;
            cnt[r] += ha + hc;
          } else {
            // overflow (rare): compress to 64 (exact-32 threshold), then
            // sequential sub-group appends (each <= 64 hits -> cnt <= 128).
            if (cnt[r] + ha > 128) {
              t[r] = rflf(rank_compress(&buf[r][0]));
              cnt[r] = 64;
              a = __ballot(d0[r] <= t[r]);
              ha = __popcll(a);
            }
            if (ha) {
              int oa = mbcnt64(a);
              if (d0[r] <= t[r])
                buf[r][cnt[r] + oa] = ((u64)monof(d0[r]) << 32) | (u32)m0;
              cnt[r] += ha;
            }
            u64 c2 = __ballot(d1[r] <= t[r]);
            int hc2 = __popcll(c2);
            if (cnt[r] + hc2 > 128) {
              t[r] = rflf(rank_compress(&buf[r][0]));
              cnt[r] = 64;
              c2 = __ballot(d1[r] <= t[r]);
              hc2 = __popcll(c2);
            }
            if (hc2) {
              int oc = mbcnt64(c2);
              if (d1[r] <= t[r])
                buf[r][cnt[r] + oc] = ((u64)monof(d1[r]) << 32) | (u32)m1;
              cnt[r] += hc2;
            }
          }
        }
      }
      mbase += 128;
    }
  }
#undef DIST

  // ---- finalize: JOINT 4-row rank-count -> per-row f64 rescore/rank-30 ----
  // cnt[r] >= 32 guaranteed (>= 32 candidates have d <= t by construction).
  // Slots >= cnt[r] hold ~0ull pads; real keys are distinct. Rank-count over
  // distinct u64 keys reproduces exactly the f32-top-32 per row.
  const double* qdb = q64 + (((size_t)b) << 12) * 8;
  {
    u64 K0[ROWS], K1[ROWS];
    int f0[ROWS], f1[ROWS];
    int cmax = 0;
#pragma unroll
    for (int r = 0; r < ROWS; ++r) {
      K0[r] = buf[r][lane];
      K1[r] = buf[r][lane + 64];
      f0[r] = 0; f1[r] = 0;
      cmax = cnt[r] > cmax ? cnt[r] : cmax;
    }
    int JJ = (cmax + 1) >> 1;
#pragma unroll 2
    for (int j = 0; j < JJ; ++j) {  // uniform addr -> LDS broadcast b128
#pragma unroll
      for (int r = 0; r < ROWS; ++r) {
        ulonglong2 kk = *(const ulonglong2*)&buf[r][2 * j];
        f0[r] += (kk.x < K0[r]) ? 1 : 0;
        f0[r] += (kk.y < K0[r]) ? 1 : 0;
        f1[r] += (kk.x < K1[r]) ? 1 : 0;
        f1[r] += (kk.y < K1[r]) ? 1 : 0;
      }
    }
#pragma unroll 1
    for (int r = 0; r < ROWS; ++r) {
      if (f0[r] < NSC) idq[wid][f0[r]] = (u32)K0[r] & (N_ - 1);
      if (f1[r] < NSC) idq[wid][f1[r]] = (u32)K1[r] & (N_ - 1);

      const double* qdr = qdb + (size_t)(r0 + r) * 8;
      double D0 = qdr[0], D1 = qdr[1], D2 = qdr[2], D3 = qdr[3], D4 = qdr[4],
             DS = qdr[5];
      u64 key = ~0ull;
      u32 myid = 0;
      if (lane < NSC) {
        myid = idq[wid][lane];
        const double* qm = qdb + (size_t)myid * 8;
        double dot = D0 * qm[0];
        dot = fma(D1, qm[1], dot);
        dot = fma(D2, qm[2], dot);
        dot = fma(D3, qm[3], dot);
        dot = fma(D4, qm[4], dot);
        double dd = (DS - 2.0 * dot) + qm[5];
        key = (monod(dd) & ~0xFFFull) | myid;
      }
      buf[r][lane] = key;  // lanes >= NSC park ~0ull in dead slots 32..63
      int rank = 0;
#pragma unroll
      for (int j = 0; j < NSC / 2; ++j) {
        ulonglong2 kk = *(const ulonglong2*)&buf[r][2 * j];
        rank += (kk.x < key) ? 1 : 0;
        rank += (kk.y < key) ? 1 : 0;
      }
      if (lane < NSC && rank < KNN) fin[wid][r][rank] = myid;
    }
  }

  // ---- overlay: stage wsm/bsm into the now-dead bufs region ----
  __syncthreads();
  float* wsm = (float*)&bufs[0][0][0];          // 13*4*33 = 1716 floats
  float* flsb = (float*)&bufs[0][0][0] + 1728;  // 16 rows x 136 = 2176 floats
  for (int i = tid; i < 13 * 128; i += 256) {
    int o = i >> 7, cc = i & 127;
    wsm[(o * 4 + (cc >> 5)) * 33 + (cc & 31)] =
        (fl == 0) ? ldv<0>(Wsem, i) : ldv<1>(Wsem, i);
  }
  if (tid < OSEM) bsm[tid] = (fl == 0) ? ldv<0>(bsem, tid) : ldv<1>(bsem, tid);
  __syncthreads();

  if (useFT) {
    // ---- packed gather: 2 rows per pass (lane>>5 selects row) ----
    int h = lane >> 5, l5 = lane & 31, c0 = l5 * 4;
#pragma unroll 1
    for (int pass = 0; pass < 2; ++pass) {
      int r = pass * 2 + h;
      float mx[4] = {-__builtin_inff(), -__builtin_inff(), -__builtin_inff(),
                     -__builtin_inff()};
      if (fl == 0)
        gather_pass<0>(b, &fin[wid][r][0], fT, c0, mx);
      else
        gather_pass<1>(b, &fin[wid][r][0], fT, c0, mx);
      float* fr = flsb + (wid * ROWS + r) * 136 + (c0 >> 5) * 33 + (c0 & 31);
      fr[0] = mx[0]; fr[1] = mx[1]; fr[2] = mx[2]; fr[3] = mx[3];
    }
    // ---- joint 4-row projection ----
    if (lane < 52) {
      int o = lane >> 2, g = lane & 3;
      const float* wr = &wsm[(o * 4 + g) * 33];
      const float* p0 = flsb + (wid * ROWS + 0) * 136 + g * 33;
      const float* p1 = flsb + (wid * ROWS + 1) * 136 + g * 33;
      const float* p2 = flsb + (wid * ROWS + 2) * 136 + g * 33;
      const float* p3 = flsb + (wid * ROWS + 3) * 136 + g * 33;
      float s0 = 0.f, s1 = 0.f, s2 = 0.f, s3 = 0.f;
#pragma unroll
      for (int c = 0; c < 32; ++c) {
        float w = wr[c];
        s0 = fmaf(w, p0[c], s0);
        s1 = fmaf(w, p1[c], s1);
        s2 = fmaf(w, p2[c], s2);
        s3 = fmaf(w, p3[c], s3);
      }
      s0 += __shfl_xor(s0, 1, 64); s0 += __shfl_xor(s0, 2, 64);
      s1 += __shfl_xor(s1, 1, 64); s1 += __shfl_xor(s1, 2, 64);
      s2 += __shfl_xor(s2, 1, 64); s2 += __shfl_xor(s2, 2, 64);
      s3 += __shfl_xor(s3, 1, 64); s3 += __shfl_xor(s3, 2, 64);
      if (g == 0) {
        size_t ob = (size_t)b * OSEM + o;
        if (fl == 0) {
          stv<0>(outv, ob * N_ + r0 + 0, s0 + bsm[o]);
          stv<0>(outv, ob * N_ + r0 + 1, s1 + bsm[o]);
          stv<0>(outv, ob * N_ + r0 + 2, s2 + bsm[o]);
          stv<0>(outv, ob * N_ + r0 + 3, s3 + bsm[o]);
        } else {
          stv<1>(outv, ob * N_ + r0 + 0, s0 + bsm[o]);
          stv<1>(outv, ob * N_ + r0 + 1, s1 + bsm[o]);
          stv<1>(outv, ob * N_ + r0 + 2, s2 + bsm[o]);
          stv<1>(outv, ob * N_ + r0 + 3, s3 + bsm[o]);
        }
      }
    }
  } else {
    // ---- fallback: legacy per-row gather from fsem layout ----
    float* fls = flsb + (wid * ROWS) * 136;
#pragma unroll 1
    for (int r = 0; r < ROWS; ++r) {
      if (fl == 0)
        gather_proj<0>(b, r0 + r, &fin[wid][r][0], fsem, wsm, bsm, fls, outv,
                       lane);
      else
        gather_proj<1>(b, r0 + r, &fin[wid][r][0], fsem, wsm, bsm, fls, outv,
                       lane);
    }
  }
}

// ---------------------------------------------------------------------------
extern "C" void kernel_launch(void* const* d_in, const int* in_sizes, int n_in,
                              void* d_out, int out_size, void* d_ws,
                              size_t ws_size, hipStream_t stream) {
  (void)in_sizes; (void)n_in; (void)out_size;
  const void* fsem = d_in[0];
  const void* fins = d_in[1];
  const void* Wad = d_in[2];
  const void* bad = d_in[3];
  const void* gad = d_in[4];
  const void* bead = d_in[5];
  const void* Wins = d_in[6];
  const void* bins = d_in[7];
  const void* Wsem = d_in[8];
  const void* bsem = d_in[9];

  char* ws = (char*)d_ws;
  u32* flag = (u32*)ws;                     // @0
  float* q32 = (float*)(ws + (1 << 20));    // @1MB, 1MB
  double* q64 = (double*)(ws + (2 << 20));  // @2MB, 2MB
  void* fT = (void*)(ws + (4 << 20));       // @4MB: bf16 8MB / f32 16MB
  int useFT0 = (ws_size >= (size_t)(13 << 20)) ? 1 : 0;
  int useFT1 = (ws_size >= (size_t)(21 << 20)) ? 1 : 0;

  void* oute_bf = (void*)((u16*)d_out + (size_t)B_ * OSEM * N_);
  void* oute_f32 = (void*)((float*)d_out + (size_t)B_ * OSEM * N_);

  k_fused<<<dim3(512), 256, 0, stream>>>(fsem, fins, Wad, bad, gad, bead,
                                         Wins, bins, q32, q64, oute_bf,
                                         oute_f32, flag);
  k_transpose<<<dim3(1024), 256, 0, stream>>>(fsem, fT, useFT0, useFT1);
  k_knn_out<<<dim3(2048), 256, 0, stream>>>(flag, q32, q64, fsem, fT, useFT0,
                                            useFT1, Wsem, bsem, d_out);
}